// Round 7
// baseline (59.133 us; speedup 1.0000x reference)
//
#include <hip/hip_runtime.h>
#include <hip/hip_bf16.h>
#include <stdint.h>

#define NPAIR 4096
#define N2    8192      // 2N rows
#define DIM   256
#define BK    64
#define NK    (DIM / BK)   // 4 K-steps
#define BM    256
#define BN    128
#define NBLK  1056         // sum_{I=0}^{31} (64 - 2I) blocks with J >= 2I
// exp(x/T) = exp2(x * log2(e)/T), T=0.5
#define EXP_SCALE 2.8853900817779268f

typedef short bf16x8 __attribute__((ext_vector_type(8)));
typedef float f32x4  __attribute__((ext_vector_type(4)));

static __device__ __forceinline__ unsigned short f2bf(float f) {
    uint32_t u = __float_as_uint(f);
    uint32_t r = (u + 0x7fffu + ((u >> 16) & 1u)) >> 16;
    return (unsigned short)r;
}

static __device__ __forceinline__ void async_copy16(void* lds, const void* g) {
    __builtin_amdgcn_global_load_lds(
        (const __attribute__((address_space(1))) void*)g,
        (__attribute__((address_space(3))) void*)lds, 16, 0, 0);
}

// ---------------- Kernel A: normalize rows + positive dot + zero rowsum ----
__global__ __launch_bounds__(256) void normalize_kernel(
    const float* __restrict__ emb_i, const float* __restrict__ emb_j,
    unsigned short* __restrict__ reps, float* __restrict__ pdot,
    float* __restrict__ rowsum) {
    int i = blockIdx.x * 4 + (threadIdx.x >> 6);
    int l = threadIdx.x & 63;       // 0..63, 4 floats each
    float4 a = ((const float4*)(emb_i + (size_t)i * DIM))[l];
    float4 b = ((const float4*)(emb_j + (size_t)i * DIM))[l];
    float si = a.x*a.x + a.y*a.y + a.z*a.z + a.w*a.w;
    float sj = b.x*b.x + b.y*b.y + b.z*b.z + b.w*b.w;
    float dp = a.x*b.x + a.y*b.y + a.z*b.z + a.w*b.w;
    #pragma unroll
    for (int off = 32; off; off >>= 1) {
        si += __shfl_xor(si, off);
        sj += __shfl_xor(sj, off);
        dp += __shfl_xor(dp, off);
    }
    float ri = 1.0f / fmaxf(sqrtf(si), 1e-12f);
    float rj = 1.0f / fmaxf(sqrtf(sj), 1e-12f);

    ushort4 ua, ub;
    ua.x = f2bf(a.x * ri); ua.y = f2bf(a.y * ri);
    ua.z = f2bf(a.z * ri); ua.w = f2bf(a.w * ri);
    ub.x = f2bf(b.x * rj); ub.y = f2bf(b.y * rj);
    ub.z = f2bf(b.z * rj); ub.w = f2bf(b.w * rj);
    *(ushort4*)(reps + (size_t)i * DIM + l * 4)            = ua;
    *(ushort4*)(reps + (size_t)(i + NPAIR) * DIM + l * 4)  = ub;

    if (l == 0) pdot[i] = dp * ri * rj;
    if (l < 2)  rowsum[2 * i + l] = 0.f;
}

// ---------- Kernel B: strict-upper sim blocks + exp + partial sums ---------
// 256x128 tiles over the strict upper triangle: M-tile I (256 rows),
// N-tile J (128 cols), J >= 2I -> 1056 blocks. Universal mask grow < gcol
// ensures each unordered pair {r,c} is computed exactly once; each computed
// element adds exp to BOTH rowsum[r] (row partial) and rowsum[c] (col
// partial) -- by symmetry this builds the full masked row sums.
// 8 waves (4M x 2N), each owns a 64x64 sub-tile; 16x16x32 bf16 MFMA; BK=64;
// single-buffered 48 KB LDS (VGPR caps at 2 blocks/CU -> 16 waves/CU TLP);
// both-sides XOR swizzle (pre-swizzled global source, swizzled ds_read).
// Per-block partials are combined across waves in LDS (overlaid on dead As)
// so only 384 atomics/block are issued; block index decorrelated by *787.
__global__ __launch_bounds__(512) void simexp_kernel(
    const unsigned short* __restrict__ reps, float* __restrict__ rowsum) {
    __shared__ __align__(16) unsigned short As[BM * BK];   // 32 KB
    __shared__ __align__(16) unsigned short Bs[BN * BK];   // 16 KB

    int t = threadIdx.x;            // 0..511
    int l = t & 63;
    int w = t >> 6;                 // 0..7
    int wr = w >> 1;                // 0..3 (M)
    int wc = w & 1;                 // 0..1 (N)

    // decorrelate + decode: idx in [0,1056), I via C(I) = 65I - I^2
    int idx = (int)((blockIdx.x * 787u) % NBLK);
    int I = (int)((65.0f - sqrtf(4225.0f - 4.0f * (float)idx)) * 0.5f);
    while (65 * I - I * I > idx) --I;
    while (65 * (I + 1) - (I + 1) * (I + 1) <= idx) ++I;
    int J = 2 * I + (idx - (65 * I - I * I));
    int brow = I * BM;
    int bcol = J * BN;

    f32x4 acc[4][4];
    #pragma unroll
    for (int mi = 0; mi < 4; ++mi)
        #pragma unroll
        for (int ni = 0; ni < 4; ++ni)
            acc[mi][ni] = (f32x4){0.f, 0.f, 0.f, 0.f};

    int frow = l & 15;
    int k16  = l >> 4;              // 0..3

    // staging addresses: 16B chunk c -> row c>>3, slot c&7 (128B rows)
    int f16r  = t >> 3;             // row base 0..63
    int slot0 = t & 7;
    int gk0   = (slot0 ^ (f16r & 7)) * 8;   // pre-swizzled k-chunk (elems)

    for (int kt = 0; kt < NK; ++kt) {
        __syncthreads();   // previous compute's ds_reads done before overwrite
        #pragma unroll
        for (int p = 0; p < 4; ++p) {    // A: 2048 chunks / 512 threads
            int r = f16r + p * 64;
            async_copy16(&As[(t + p * 512) * 8],
                         reps + (size_t)(brow + r) * DIM + kt * BK + gk0);
        }
        #pragma unroll
        for (int p = 0; p < 2; ++p) {    // B: 1024 chunks / 512 threads
            int r = f16r + p * 64;
            async_copy16(&Bs[(t + p * 512) * 8],
                         reps + (size_t)(bcol + r) * DIM + kt * BK + gk0);
        }
        asm volatile("s_waitcnt vmcnt(0)" ::: "memory");
        __syncthreads();

        #pragma unroll
        for (int kk = 0; kk < 2; ++kk) {
            bf16x8 afr[4], bfr[4];
            #pragma unroll
            for (int ni = 0; ni < 4; ++ni) {
                int r    = wc * 64 + ni * 16 + frow;
                int slot = (kk * 4 + k16) ^ (r & 7);
                bfr[ni] = *(const bf16x8*)&Bs[r * BK + slot * 8];
            }
            #pragma unroll
            for (int mi = 0; mi < 4; ++mi) {
                int r    = wr * 64 + mi * 16 + frow;
                int slot = (kk * 4 + k16) ^ (r & 7);
                afr[mi] = *(const bf16x8*)&As[r * BK + slot * 8];
            }
            #pragma unroll
            for (int mi = 0; mi < 4; ++mi)
                #pragma unroll
                for (int ni = 0; ni < 4; ++ni)
                    acc[mi][ni] = __builtin_amdgcn_mfma_f32_16x16x32_bf16(
                        afr[mi], bfr[ni], acc[mi][ni], 0, 0, 0);
        }
    }

    // Epilogue. C/D layout: col = lane&15, row = (lane>>4)*4 + j  [m89/m91]
    // Strict-upper mask grow<gcol. csum[ni]: col partials; rv: row total for
    // row roff = k16*4 + (frow>>2)*16 + (frow&3) of this wave's sub-tile.
    int rbase = brow + wr * 64 + k16 * 4;
    int cb    = bcol + wc * 64 + frow;
    float csum[4] = {0.f, 0.f, 0.f, 0.f};
    float rv = 0.f;
    #pragma unroll
    for (int mi = 0; mi < 4; ++mi) {
        #pragma unroll
        for (int j = 0; j < 4; ++j) {
            int grow = rbase + mi * 16 + j;
            float rp = 0.f;
            #pragma unroll
            for (int ni = 0; ni < 4; ++ni) {
                float e = exp2f(acc[mi][ni][j] * EXP_SCALE);
                e = (grow < cb + ni * 16) ? e : 0.f;   // strict upper only
                csum[ni] += e;
                rp += e;
            }
            rp += __shfl_xor(rp, 1);
            rp += __shfl_xor(rp, 2);
            rp += __shfl_xor(rp, 4);
            rp += __shfl_xor(rp, 8);
            rv = (frow == mi * 4 + j) ? rp : rv;
        }
    }
    #pragma unroll
    for (int ni = 0; ni < 4; ++ni) {      // col totals: reduce k16 groups
        csum[ni] += __shfl_xor(csum[ni], 16);
        csum[ni] += __shfl_xor(csum[ni], 32);
    }
    float cv = csum[0];
    #pragma unroll
    for (int v = 1; v < 4; ++v) cv = (k16 == v) ? csum[v] : cv;  // static idx

    // cross-wave combine in LDS overlaid on As (dead after barrier)
    __syncthreads();
    float* cred = (float*)As;            // [4 wr][128 cols]   = 2 KB
    float* rred = cred + 512;            // [2 wc][256 rows]   = 2 KB
    int c    = wc * 64 + k16 * 16 + frow;               // 0..127
    int roff = k16 * 4 + (frow >> 2) * 16 + (frow & 3); // 0..63 bijection
    cred[wr * 128 + c] = cv;
    rred[wc * 256 + wr * 64 + roff] = rv;
    __syncthreads();

    if (t < 128) {
        float v = cred[t] + cred[128 + t] + cred[256 + t] + cred[384 + t];
        atomicAdd(&rowsum[bcol + t], v);
    } else if (t < 384) {
        int r = t - 128;
        float v = rred[r] + rred[256 + r];
        atomicAdd(&rowsum[brow + r], v);
    }
}

// ---------------- Kernel C: finalize ----------------
__global__ __launch_bounds__(256) void finalize_kernel(
    const float* __restrict__ rowsum, const float* __restrict__ pdot,
    float* __restrict__ out) {
    int t = threadIdx.x;
    const float4* rs4 = (const float4*)rowsum;
    const float4* pd4 = (const float4*)pdot;
    float s = 0.f, p = 0.f;
    for (int r = t; r < N2 / 4; r += 256) {
        float4 v = rs4[r];
        s += logf(v.x) + logf(v.y) + logf(v.z) + logf(v.w);
    }
    for (int r = t; r < NPAIR / 4; r += 256) {
        float4 v = pd4[r];
        p += v.x + v.y + v.z + v.w;
    }
    #pragma unroll
    for (int off = 32; off; off >>= 1) {
        s += __shfl_xor(s, off);
        p += __shfl_xor(p, off);
    }
    __shared__ float reds[4], redp[4];
    if ((t & 63) == 0) { reds[t >> 6] = s; redp[t >> 6] = p; }
    __syncthreads();
    if (t == 0) {
        float S = reds[0] + reds[1] + reds[2] + reds[3];
        float P = redp[0] + redp[1] + redp[2] + redp[3];
        // loss = (sum log D - (2/T)*2*sum(dp)) / 2N ; (2/T)*2 folded: 4*P
        out[0] = (S - 4.0f * P) / (float)N2;
    }
}

extern "C" void kernel_launch(void* const* d_in, const int* in_sizes, int n_in,
                              void* d_out, int out_size, void* d_ws, size_t ws_size,
                              hipStream_t stream) {
    const float* emb_i = (const float*)d_in[0];
    const float* emb_j = (const float*)d_in[1];
    float* out = (float*)d_out;

    char* ws = (char*)d_ws;
    float*          rowsum = (float*)ws;                    // 8192 * 4 B
    float*          pdot   = (float*)(ws + 32768);          // 4096 * 4 B
    unsigned short* reps   = (unsigned short*)(ws + 65536); // 8192*256*2 B

    normalize_kernel<<<NPAIR / 4, 256, 0, stream>>>(emb_i, emb_j, reps, pdot,
                                                    rowsum);

    simexp_kernel<<<NBLK, 512, 0, stream>>>(reps, rowsum);

    finalize_kernel<<<1, 256, 0, stream>>>(rowsum, pdot, out);
}

// Round 8
// 53.467 us; speedup vs baseline: 1.1060x; 1.1060x over previous
//
#include <hip/hip_runtime.h>
#include <hip/hip_bf16.h>
#include <stdint.h>

#define NPAIR 4096
#define N2    8192      // 2N rows
#define DIM   256
#define BK    128
#define NROUND (DIM / BK)  // 2 staging rounds
#define NBLOCKS 2080       // 64*65/2 upper-triangle 128x128 blocks
// exp(x/T) = exp2(x * log2(e)/T), T=0.5
#define EXP_SCALE 2.8853900817779268f

typedef short bf16x8 __attribute__((ext_vector_type(8)));
typedef float f32x4  __attribute__((ext_vector_type(4)));

static __device__ __forceinline__ unsigned short f2bf(float f) {
    uint32_t u = __float_as_uint(f);
    uint32_t r = (u + 0x7fffu + ((u >> 16) & 1u)) >> 16;
    return (unsigned short)r;
}

static __device__ __forceinline__ void async_copy16(void* lds, const void* g) {
    __builtin_amdgcn_global_load_lds(
        (const __attribute__((address_space(1))) void*)g,
        (__attribute__((address_space(3))) void*)lds, 16, 0, 0);
}

// ---------------- Kernel A: normalize rows + positive dot + zero rowsum ----
__global__ __launch_bounds__(256) void normalize_kernel(
    const float* __restrict__ emb_i, const float* __restrict__ emb_j,
    unsigned short* __restrict__ reps, float* __restrict__ pdot,
    float* __restrict__ rowsum) {
    int i = blockIdx.x * 4 + (threadIdx.x >> 6);
    int l = threadIdx.x & 63;       // 0..63, 4 floats each
    float4 a = ((const float4*)(emb_i + (size_t)i * DIM))[l];
    float4 b = ((const float4*)(emb_j + (size_t)i * DIM))[l];
    float si = a.x*a.x + a.y*a.y + a.z*a.z + a.w*a.w;
    float sj = b.x*b.x + b.y*b.y + b.z*b.z + b.w*b.w;
    float dp = a.x*b.x + a.y*b.y + a.z*b.z + a.w*b.w;
    #pragma unroll
    for (int off = 32; off; off >>= 1) {
        si += __shfl_xor(si, off);
        sj += __shfl_xor(sj, off);
        dp += __shfl_xor(dp, off);
    }
    float ri = 1.0f / fmaxf(sqrtf(si), 1e-12f);
    float rj = 1.0f / fmaxf(sqrtf(sj), 1e-12f);

    ushort4 ua, ub;
    ua.x = f2bf(a.x * ri); ua.y = f2bf(a.y * ri);
    ua.z = f2bf(a.z * ri); ua.w = f2bf(a.w * ri);
    ub.x = f2bf(b.x * rj); ub.y = f2bf(b.y * rj);
    ub.z = f2bf(b.z * rj); ub.w = f2bf(b.w * rj);
    *(ushort4*)(reps + (size_t)i * DIM + l * 4)            = ua;
    *(ushort4*)(reps + (size_t)(i + NPAIR) * DIM + l * 4)  = ub;

    if (l == 0) pdot[i] = dp * ri * rj;
    if (l < 2)  rowsum[2 * i + l] = 0.f;
}

// ---------- Kernel B: upper-triangle sim blocks + exp + partial sums -------
// Skinny-K schedule: BK=128 -> only 2 staging rounds and 3 barriers per
// block. Each round: burst of 16 global_load_lds per thread (latency
// amortized over the burst), one vmcnt(0)+barrier, then 4 uninterrupted
// kk-windows of MFMA. 128x128 tile, 4 waves (2x2, 64x64 each),
// single-buffered 64 KB LDS (2 blocks/CU -> cross-block overlap of burst
// and compute). 256B LDS rows, XOR swizzle slot^=(row&15), both-sides
// (pre-swizzled global source + swizzled ds_read; rule #21).
// Triangle in anti-diagonal order (r6); every block adds COLUMN partials to
// rowsum[cols]; off-diagonal blocks also add ROW partials (exp(sim/T) is
// symmetric); diagonal blocks mask the main diagonal and skip row atomics.
// Per-block cross-wave combine in LDS -> 256 atomics/block.
__global__ __launch_bounds__(256) void simexp_kernel(
    const unsigned short* __restrict__ reps, float* __restrict__ rowsum) {
    __shared__ __align__(16) unsigned short As[128 * BK];   // 32 KB
    __shared__ __align__(16) unsigned short Bs[128 * BK];   // 32 KB

    int t = threadIdx.x;
    int l = t & 63;
    int w = t >> 6;
    int wr = w >> 1, wc = w & 1;

    // anti-diagonal decode: C(d) = d*(129-d)/2 blocks before diagonal d
    int idx = blockIdx.x;
    int d = (int)((129.0f - sqrtf(129.0f * 129.0f - 8.0f * (float)idx)) * 0.5f);
    while (d * (129 - d) / 2 > idx) --d;
    while ((d + 1) * (128 - d) / 2 <= idx) ++d;
    int i0 = idx - d * (129 - d) / 2;
    int brow = i0 * 128;
    int bcol = (i0 + d) * 128;
    bool diag = (d == 0);

    f32x4 acc[4][4];
    #pragma unroll
    for (int mi = 0; mi < 4; ++mi)
        #pragma unroll
        for (int ni = 0; ni < 4; ++ni)
            acc[mi][ni] = (f32x4){0.f, 0.f, 0.f, 0.f};

    int frow = l & 15;
    int k16  = l >> 4;              // 0..3

    // staging: 16B chunk c (=t+p*256) -> row c>>4, slot c&15 (256B rows)
    // r&15 == (t>>4)&15 for all p (p adds multiples of 16), so gk0 is fixed.
    int rb  = t >> 4;                         // row base 0..15
    int gk0 = ((t & 15) ^ (rb & 15)) * 8;     // pre-swizzled k-chunk (elems)

    for (int kt = 0; kt < NROUND; ++kt) {
        if (kt) __syncthreads();   // previous round's ds_reads complete
        #pragma unroll
        for (int p = 0; p < 8; ++p) {         // A: 2048 chunks / 256 thr
            int r = rb + p * 16;
            async_copy16(&As[(t + p * 256) * 8],
                         reps + (size_t)(brow + r) * DIM + kt * BK + gk0);
        }
        #pragma unroll
        for (int p = 0; p < 8; ++p) {         // B: 2048 chunks / 256 thr
            int r = rb + p * 16;
            async_copy16(&Bs[(t + p * 256) * 8],
                         reps + (size_t)(bcol + r) * DIM + kt * BK + gk0);
        }
        asm volatile("s_waitcnt vmcnt(0)" ::: "memory");
        __syncthreads();

        #pragma unroll
        for (int kk = 0; kk < 4; ++kk) {
            bf16x8 afr[4], bfr[4];
            #pragma unroll
            for (int ni = 0; ni < 4; ++ni) {
                int r    = wc * 64 + ni * 16 + frow;
                int slot = (kk * 4 + k16) ^ (r & 15);
                bfr[ni] = *(const bf16x8*)&Bs[r * BK + slot * 8];
            }
            #pragma unroll
            for (int mi = 0; mi < 4; ++mi) {
                int r    = wr * 64 + mi * 16 + frow;
                int slot = (kk * 4 + k16) ^ (r & 15);
                afr[mi] = *(const bf16x8*)&As[r * BK + slot * 8];
            }
            #pragma unroll
            for (int mi = 0; mi < 4; ++mi)
                #pragma unroll
                for (int ni = 0; ni < 4; ++ni)
                    acc[mi][ni] = __builtin_amdgcn_mfma_f32_16x16x32_bf16(
                        afr[mi], bfr[ni], acc[mi][ni], 0, 0, 0);
        }
    }

    // Epilogue. C/D layout: col = lane&15, row = (lane>>4)*4 + j  [m89/m91]
    int rbase = brow + wr * 64 + k16 * 4;
    int cb    = bcol + wc * 64 + frow;
    float csum[4] = {0.f, 0.f, 0.f, 0.f};
    float rv = 0.f;
    #pragma unroll
    for (int mi = 0; mi < 4; ++mi) {
        #pragma unroll
        for (int j = 0; j < 4; ++j) {
            int grow = rbase + mi * 16 + j;
            float rp = 0.f;
            #pragma unroll
            for (int ni = 0; ni < 4; ++ni) {
                float e = exp2f(acc[mi][ni][j] * EXP_SCALE);
                e = (grow == cb + ni * 16) ? 0.f : e;   // main diagonal only
                csum[ni] += e;
                rp += e;
            }
            rp += __shfl_xor(rp, 1);
            rp += __shfl_xor(rp, 2);
            rp += __shfl_xor(rp, 4);
            rp += __shfl_xor(rp, 8);
            rv = (frow == mi * 4 + j) ? rp : rv;
        }
    }
    // column totals within wave: reduce over k16 groups
    #pragma unroll
    for (int ni = 0; ni < 4; ++ni) {
        csum[ni] += __shfl_xor(csum[ni], 16);
        csum[ni] += __shfl_xor(csum[ni], 32);
    }
    float cv = csum[0];
    #pragma unroll
    for (int v = 1; v < 4; ++v) cv = (k16 == v) ? csum[v] : cv;  // static idx

    // cross-wave combine through LDS aliased onto As (dead after barrier)
    __syncthreads();
    float* red = (float*)&As[0];        // [0..255]=cred, [256..511]=rred
    red[w * 64 + l] = cv;               // col partial: col = bcol+(w&1)*64+l
    int roff = k16 * 4 + (frow >> 2) * 16 + (frow & 3);  // bijection on 0..63
    red[256 + w * 64 + roff] = rv;      // row partial: row = brow+(w>>1)*64+roff
    __syncthreads();

    if (w < 2) {        // waves 0,1: finalize 128 column atomics
        float v = red[w * 64 + l] + red[(w + 2) * 64 + l];
        atomicAdd(&rowsum[bcol + w * 64 + l], v);
    } else if (!diag) { // waves 2,3: finalize 128 row atomics
        int half = w - 2;
        float v = red[256 + (2 * half) * 64 + l] + red[256 + (2 * half + 1) * 64 + l];
        atomicAdd(&rowsum[brow + half * 64 + l], v);
    }
}

// ---------------- Kernel C: finalize ----------------
__global__ __launch_bounds__(256) void finalize_kernel(
    const float* __restrict__ rowsum, const float* __restrict__ pdot,
    float* __restrict__ out) {
    int t = threadIdx.x;
    const float4* rs4 = (const float4*)rowsum;
    const float4* pd4 = (const float4*)pdot;
    float s = 0.f, p = 0.f;
    for (int r = t; r < N2 / 4; r += 256) {
        float4 v = rs4[r];
        s += logf(v.x) + logf(v.y) + logf(v.z) + logf(v.w);
    }
    for (int r = t; r < NPAIR / 4; r += 256) {
        float4 v = pd4[r];
        p += v.x + v.y + v.z + v.w;
    }
    #pragma unroll
    for (int off = 32; off; off >>= 1) {
        s += __shfl_xor(s, off);
        p += __shfl_xor(p, off);
    }
    __shared__ float reds[4], redp[4];
    if ((t & 63) == 0) { reds[t >> 6] = s; redp[t >> 6] = p; }
    __syncthreads();
    if (t == 0) {
        float S = reds[0] + reds[1] + reds[2] + reds[3];
        float P = redp[0] + redp[1] + redp[2] + redp[3];
        // loss = (sum log D - (2/T)*2*sum(dp)) / 2N ; (2/T)*2 folded: 4*P
        out[0] = (S - 4.0f * P) / (float)N2;
    }
}

extern "C" void kernel_launch(void* const* d_in, const int* in_sizes, int n_in,
                              void* d_out, int out_size, void* d_ws, size_t ws_size,
                              hipStream_t stream) {
    const float* emb_i = (const float*)d_in[0];
    const float* emb_j = (const float*)d_in[1];
    float* out = (float*)d_out;

    char* ws = (char*)d_ws;
    float*          rowsum = (float*)ws;                    // 8192 * 4 B
    float*          pdot   = (float*)(ws + 32768);          // 4096 * 4 B
    unsigned short* reps   = (unsigned short*)(ws + 65536); // 8192*256*2 B

    normalize_kernel<<<NPAIR / 4, 256, 0, stream>>>(emb_i, emb_j, reps, pdot,
                                                    rowsum);

    simexp_kernel<<<NBLOCKS, 256, 0, stream>>>(reps, rowsum);

    finalize_kernel<<<1, 256, 0, stream>>>(rowsum, pdot, out);
}

// Round 9
// 47.528 us; speedup vs baseline: 1.2442x; 1.1250x over previous
//
#include <hip/hip_runtime.h>
#include <hip/hip_bf16.h>
#include <stdint.h>

#define NPAIR 4096
#define N2    8192      // 2N rows
#define DIM   256
#define NBLOCKS 2080    // 64*65/2 upper-triangle 128x128 blocks
// exp(x/T) = exp2(x * log2(e)/T), T=0.5
#define EXP_SCALE 2.8853900817779268f

typedef short bf16x8 __attribute__((ext_vector_type(8)));
typedef float f32x4  __attribute__((ext_vector_type(4)));

static __device__ __forceinline__ unsigned short f2bf(float f) {
    uint32_t u = __float_as_uint(f);
    uint32_t r = (u + 0x7fffu + ((u >> 16) & 1u)) >> 16;
    return (unsigned short)r;
}

// reps is stored FRAGMENT-TILED: ushort index of (row i, dim d) =
//   ((i>>4)*32 + (d>>3))*128 + (i&15)*8 + (d&7)
// so an MFMA A/B fragment load (16 rows x 8 k, lane l -> row l&15,
// k-slot l>>4) is the contiguous 1KB block at tile(i>>4, d>>3): lane l
// reads 16B at base + l*16. One fully-coalesced global_load_dwordx4/wave.

// ---------------- Kernel A: normalize rows + positive dot + zero rowsum ----
__global__ __launch_bounds__(256) void normalize_kernel(
    const float* __restrict__ emb_i, const float* __restrict__ emb_j,
    unsigned short* __restrict__ reps, float* __restrict__ pdot,
    float* __restrict__ rowsum) {
    int i = blockIdx.x * 4 + (threadIdx.x >> 6);
    int l = threadIdx.x & 63;       // 0..63, 4 floats each
    float4 a = ((const float4*)(emb_i + (size_t)i * DIM))[l];
    float4 b = ((const float4*)(emb_j + (size_t)i * DIM))[l];
    float si = a.x*a.x + a.y*a.y + a.z*a.z + a.w*a.w;
    float sj = b.x*b.x + b.y*b.y + b.z*b.z + b.w*b.w;
    float dp = a.x*b.x + a.y*b.y + a.z*b.z + a.w*b.w;
    #pragma unroll
    for (int off = 32; off; off >>= 1) {
        si += __shfl_xor(si, off);
        sj += __shfl_xor(sj, off);
        dp += __shfl_xor(dp, off);
    }
    float ri = 1.0f / fmaxf(sqrtf(si), 1e-12f);
    float rj = 1.0f / fmaxf(sqrtf(sj), 1e-12f);

    ushort4 ua, ub;
    ua.x = f2bf(a.x * ri); ua.y = f2bf(a.y * ri);
    ua.z = f2bf(a.z * ri); ua.w = f2bf(a.w * ri);
    ub.x = f2bf(b.x * rj); ub.y = f2bf(b.y * rj);
    ub.z = f2bf(b.z * rj); ub.w = f2bf(b.w * rj);

    // tiled store: row i, d0 = 4l  (k-tile = l>>1, k-within = (l&1)*4)
    int ii = i + NPAIR;
    int idxA = ((i  >> 4) * 32 + (l >> 1)) * 128 + (i  & 15) * 8 + (l & 1) * 4;
    int idxB = ((ii >> 4) * 32 + (l >> 1)) * 128 + (ii & 15) * 8 + (l & 1) * 4;
    *(ushort4*)(reps + idxA) = ua;
    *(ushort4*)(reps + idxB) = ub;

    if (l == 0) pdot[i] = dp * ri * rj;
    if (l < 2)  rowsum[2 * i + l] = 0.f;
}

// ---------- Kernel B: upper-triangle sim blocks, DIRECT-FROM-L2 -----------
// No tile staging: reps (4 MB, tiled layout) is L2-resident; each wave loads
// its MFMA fragments directly with fully-coalesced 1KB global_load_dwordx4.
// Zero barriers in the main loop; depth-2 register pipeline (static bufs).
// 128x128 tile, 4 waves (2x2, 64x64 each), 16x16x32 bf16 MFMA.
// Triangle in anti-diagonal order; every block adds COLUMN partials to
// rowsum[cols]; off-diagonal blocks also add ROW partials (exp(sim/T)
// symmetric); diagonal blocks mask the main diagonal, skip row atomics.
// Cross-wave combine in (tiny) LDS -> 256 atomics/block.
__global__ __launch_bounds__(256, 3) void simexp_kernel(
    const unsigned short* __restrict__ reps, float* __restrict__ rowsum) {
    __shared__ float red[512];      // 2 KB: [0..255]=col, [256..511]=row

    int t = threadIdx.x;
    int l = t & 63;
    int w = t >> 6;
    int wr = w >> 1, wc = w & 1;

    // anti-diagonal decode: C(d) = d*(129-d)/2 blocks before diagonal d
    int idx = blockIdx.x;
    int d = (int)((129.0f - sqrtf(129.0f * 129.0f - 8.0f * (float)idx)) * 0.5f);
    while (d * (129 - d) / 2 > idx) --d;
    while ((d + 1) * (128 - d) / 2 <= idx) ++d;
    int i0 = idx - d * (129 - d) / 2;
    int brow = i0 * 128;
    int bcol = (i0 + d) * 128;
    bool diag = (d == 0);

    // row-tile indices for this wave's A (rows) and B (cols) fragments
    int R0A = (brow >> 4) + wr * 4;     // + mi
    int R0B = (bcol >> 4) + wc * 4;     // + ni

    f32x4 acc[4][4];
    #pragma unroll
    for (int mi = 0; mi < 4; ++mi)
        #pragma unroll
        for (int ni = 0; ni < 4; ++ni)
            acc[mi][ni] = (f32x4){0.f, 0.f, 0.f, 0.f};

    // fragment tile (rowtile R, ktile kw*4..): contiguous 1KB at
    // ushort offset (R*32 + kw*4)*128 + l*8
    #define LOADF(dstA, dstB, kw)                                              \
        _Pragma("unroll")                                                      \
        for (int q = 0; q < 4; ++q) {                                          \
            dstA[q] = ((const bf16x8*)(reps +                                  \
                       (size_t)(((R0A + q) * 32 + (kw) * 4) * 128)))[l];       \
            dstB[q] = ((const bf16x8*)(reps +                                  \
                       (size_t)(((R0B + q) * 32 + (kw) * 4) * 128)))[l];       \
        }
    #define MM(a, b)                                                           \
        _Pragma("unroll")                                                      \
        for (int mi = 0; mi < 4; ++mi)                                         \
            _Pragma("unroll")                                                  \
            for (int ni = 0; ni < 4; ++ni)                                     \
                acc[mi][ni] = __builtin_amdgcn_mfma_f32_16x16x32_bf16(         \
                    a[mi], b[ni], acc[mi][ni], 0, 0, 0);

    bf16x8 a0[4], b0[4], a1[4], b1[4];
    LOADF(a0, b0, 0);
    LOADF(a1, b1, 1);
    #pragma unroll
    for (int kw = 0; kw < 8; ++kw) {        // 8 k-windows of 32
        if ((kw & 1) == 0) {
            MM(a0, b0);
            if (kw + 2 < 8) { LOADF(a0, b0, kw + 2); }
        } else {
            MM(a1, b1);
            if (kw + 2 < 8) { LOADF(a1, b1, kw + 2); }
        }
    }
    #undef LOADF
    #undef MM

    // Epilogue. C/D layout: col = lane&15, row = (lane>>4)*4 + j  [m89/m91]
    int frow = l & 15;
    int k16  = l >> 4;
    int rbase = brow + wr * 64 + k16 * 4;
    int cb    = bcol + wc * 64 + frow;
    float csum[4] = {0.f, 0.f, 0.f, 0.f};
    float rv = 0.f;
    #pragma unroll
    for (int mi = 0; mi < 4; ++mi) {
        #pragma unroll
        for (int j = 0; j < 4; ++j) {
            int grow = rbase + mi * 16 + j;
            float rp = 0.f;
            #pragma unroll
            for (int ni = 0; ni < 4; ++ni) {
                float e = exp2f(acc[mi][ni][j] * EXP_SCALE);
                e = (grow == cb + ni * 16) ? 0.f : e;   // main diagonal only
                csum[ni] += e;
                rp += e;
            }
            rp += __shfl_xor(rp, 1);
            rp += __shfl_xor(rp, 2);
            rp += __shfl_xor(rp, 4);
            rp += __shfl_xor(rp, 8);
            rv = (frow == mi * 4 + j) ? rp : rv;
        }
    }
    // column totals within wave: reduce over k16 groups
    #pragma unroll
    for (int ni = 0; ni < 4; ++ni) {
        csum[ni] += __shfl_xor(csum[ni], 16);
        csum[ni] += __shfl_xor(csum[ni], 32);
    }
    float cv = csum[0];
    #pragma unroll
    for (int v = 1; v < 4; ++v) cv = (k16 == v) ? csum[v] : cv;  // static idx

    // cross-wave combine through LDS
    red[w * 64 + l] = cv;               // col partial: col = bcol+(w&1)*64+l
    int roff = k16 * 4 + (frow >> 2) * 16 + (frow & 3);  // bijection on 0..63
    red[256 + w * 64 + roff] = rv;      // row partial: row = brow+(w>>1)*64+roff
    __syncthreads();

    if (w < 2) {        // waves 0,1: finalize 128 column atomics
        float v = red[w * 64 + l] + red[(w + 2) * 64 + l];
        atomicAdd(&rowsum[bcol + w * 64 + l], v);
    } else if (!diag) { // waves 2,3: finalize 128 row atomics
        int half = w - 2;
        float v = red[256 + (2 * half) * 64 + l] + red[256 + (2 * half + 1) * 64 + l];
        atomicAdd(&rowsum[brow + half * 64 + l], v);
    }
}

// ---------------- Kernel C: finalize ----------------
__global__ __launch_bounds__(256) void finalize_kernel(
    const float* __restrict__ rowsum, const float* __restrict__ pdot,
    float* __restrict__ out) {
    int t = threadIdx.x;
    const float4* rs4 = (const float4*)rowsum;
    const float4* pd4 = (const float4*)pdot;
    float s = 0.f, p = 0.f;
    for (int r = t; r < N2 / 4; r += 256) {
        float4 v = rs4[r];
        s += logf(v.x) + logf(v.y) + logf(v.z) + logf(v.w);
    }
    for (int r = t; r < NPAIR / 4; r += 256) {
        float4 v = pd4[r];
        p += v.x + v.y + v.z + v.w;
    }
    #pragma unroll
    for (int off = 32; off; off >>= 1) {
        s += __shfl_xor(s, off);
        p += __shfl_xor(p, off);
    }
    __shared__ float reds[4], redp[4];
    if ((t & 63) == 0) { reds[t >> 6] = s; redp[t >> 6] = p; }
    __syncthreads();
    if (t == 0) {
        float S = reds[0] + reds[1] + reds[2] + reds[3];
        float P = redp[0] + redp[1] + redp[2] + redp[3];
        // loss = (sum log D - (2/T)*2*sum(dp)) / 2N ; (2/T)*2 folded: 4*P
        out[0] = (S - 4.0f * P) / (float)N2;
    }
}

extern "C" void kernel_launch(void* const* d_in, const int* in_sizes, int n_in,
                              void* d_out, int out_size, void* d_ws, size_t ws_size,
                              hipStream_t stream) {
    const float* emb_i = (const float*)d_in[0];
    const float* emb_j = (const float*)d_in[1];
    float* out = (float*)d_out;

    char* ws = (char*)d_ws;
    float*          rowsum = (float*)ws;                    // 8192 * 4 B
    float*          pdot   = (float*)(ws + 32768);          // 4096 * 4 B
    unsigned short* reps   = (unsigned short*)(ws + 65536); // 8192*256*2 B (tiled)

    normalize_kernel<<<NPAIR / 4, 256, 0, stream>>>(emb_i, emb_j, reps, pdot,
                                                    rowsum);

    simexp_kernel<<<NBLOCKS, 256, 0, stream>>>(reps, rowsum);

    finalize_kernel<<<1, 256, 0, stream>>>(rowsum, pdot, out);
}

// Round 10
// 44.632 us; speedup vs baseline: 1.3249x; 1.0649x over previous
//
#include <hip/hip_runtime.h>
#include <hip/hip_bf16.h>
#include <hip/hip_fp8.h>
#include <stdint.h>

#define NPAIR 4096
#define N2    8192      // 2N rows
#define DIM   256
#define NBLOCKS 2080    // 64*65/2 upper-triangle 128x128 blocks
// exp(x/T) = exp2(x * log2(e)/T), T=0.5
#define EXP_SCALE 2.8853900817779268f

typedef long  f8frag;   // 8 fp8 elems = 2 VGPR (A/B operand of 16x16x32 fp8)
typedef float f32x4 __attribute__((ext_vector_type(4)));

static __device__ __forceinline__ uint8_t f2fp8(float f) {
    __hip_fp8_e4m3 v(f);                 // OCP e4m3fn, RNE saturating
    return *reinterpret_cast<uint8_t*>(&v);
}

// reps is stored FRAGMENT-TILED fp8: byte index of (row i, dim d) =
//   ((i>>4)*8 + (d>>5))*512 + ((d>>3)&3)*128 + (i&15)*8 + (d&7)
// so an MFMA fragment (16 rows x 32 k; lane l -> row l&15, k-slot l>>4)
// is the contiguous 512B block at tile(i>>4, d>>5): lane l reads 8B at
// base + l*8. One fully-coalesced 512B global_load_dwordx2 per wave.

// ---------------- Kernel A: normalize rows + positive dot + zero rowsum ----
__global__ __launch_bounds__(256) void normalize_kernel(
    const float* __restrict__ emb_i, const float* __restrict__ emb_j,
    uint8_t* __restrict__ reps, float* __restrict__ pdot,
    float* __restrict__ rowsum) {
    int i = blockIdx.x * 4 + (threadIdx.x >> 6);
    int l = threadIdx.x & 63;       // 0..63, 4 floats each
    float4 a = ((const float4*)(emb_i + (size_t)i * DIM))[l];
    float4 b = ((const float4*)(emb_j + (size_t)i * DIM))[l];
    float si = a.x*a.x + a.y*a.y + a.z*a.z + a.w*a.w;
    float sj = b.x*b.x + b.y*b.y + b.z*b.z + b.w*b.w;
    float dp = a.x*b.x + a.y*b.y + a.z*b.z + a.w*b.w;
    #pragma unroll
    for (int off = 32; off; off >>= 1) {
        si += __shfl_xor(si, off);
        sj += __shfl_xor(sj, off);
        dp += __shfl_xor(dp, off);
    }
    float ri = 1.0f / fmaxf(sqrtf(si), 1e-12f);
    float rj = 1.0f / fmaxf(sqrtf(sj), 1e-12f);

    uchar4 ua, ub;
    ua.x = f2fp8(a.x * ri); ua.y = f2fp8(a.y * ri);
    ua.z = f2fp8(a.z * ri); ua.w = f2fp8(a.w * ri);
    ub.x = f2fp8(b.x * rj); ub.y = f2fp8(b.y * rj);
    ub.z = f2fp8(b.z * rj); ub.w = f2fp8(b.w * rj);

    // tiled store: row i, d0 = 4l -> ktile l>>3, slot (l>>1)&3, e (l&1)*4
    int ii = i + NPAIR;
    int idxA = (((i  >> 4) * 8 + (l >> 3)) * 512) + ((l >> 1) & 3) * 128
             + (i  & 15) * 8 + (l & 1) * 4;
    int idxB = (((ii >> 4) * 8 + (l >> 3)) * 512) + ((l >> 1) & 3) * 128
             + (ii & 15) * 8 + (l & 1) * 4;
    *(uchar4*)(reps + idxA) = ua;
    *(uchar4*)(reps + idxB) = ub;

    if (l == 0) pdot[i] = dp * ri * rj;
    if (l < 2)  rowsum[2 * i + l] = 0.f;
}

// ---------- Kernel B: upper-triangle sim blocks, fp8 DIRECT-FROM-L2 -------
// No tile staging: reps (2 MB fp8, tiled) is L2-resident; fragments loaded
// directly with coalesced 512B global_load_dwordx2; zero main-loop barriers;
// depth-2 register pipeline (static bufs). 128x128 tile, 4 waves (2x2),
// 16x16x32 fp8_fp8 MFMA (bf16-rate, half the bytes). Denominator-only fp8:
// positives use fp32 pdot. Triangle in anti-diagonal order; column partials
// to rowsum[cols], row partials (symmetry) to rowsum[rows]; diagonal blocks
// mask the main diagonal, skip row atomics. LDS combine -> 256 atomics/blk.
__global__ __launch_bounds__(256, 4) void simexp_kernel(
    const uint8_t* __restrict__ reps, float* __restrict__ rowsum) {
    __shared__ float red[512];      // 2 KB: [0..255]=col, [256..511]=row

    int t = threadIdx.x;
    int l = t & 63;
    int w = t >> 6;
    int wr = w >> 1, wc = w & 1;

    // anti-diagonal decode: C(d) = d*(129-d)/2 blocks before diagonal d
    int idx = blockIdx.x;
    int d = (int)((129.0f - sqrtf(129.0f * 129.0f - 8.0f * (float)idx)) * 0.5f);
    while (d * (129 - d) / 2 > idx) --d;
    while ((d + 1) * (128 - d) / 2 <= idx) ++d;
    int i0 = idx - d * (129 - d) / 2;
    int brow = i0 * 128;
    int bcol = (i0 + d) * 128;
    bool diag = (d == 0);

    // row-tile indices for this wave's A (rows) and B (cols) fragments
    int R0A = (brow >> 4) + wr * 4;     // + mi
    int R0B = (bcol >> 4) + wc * 4;     // + ni

    f32x4 acc[4][4];
    #pragma unroll
    for (int mi = 0; mi < 4; ++mi)
        #pragma unroll
        for (int ni = 0; ni < 4; ++ni)
            acc[mi][ni] = (f32x4){0.f, 0.f, 0.f, 0.f};

    // fragment tile (rowtile R, ktile kw): contiguous 512B at byte
    // (R*8 + kw)*512; lane l reads 8B at + l*8
    #define LOADF(dstA, dstB, kw)                                              \
        _Pragma("unroll")                                                      \
        for (int q = 0; q < 4; ++q) {                                          \
            dstA[q] = ((const f8frag*)(reps +                                  \
                       (size_t)(((R0A + q) * 8 + (kw)) * 512)))[l];            \
            dstB[q] = ((const f8frag*)(reps +                                  \
                       (size_t)(((R0B + q) * 8 + (kw)) * 512)))[l];            \
        }
    #define MM(a, b)                                                           \
        _Pragma("unroll")                                                      \
        for (int mi = 0; mi < 4; ++mi)                                         \
            _Pragma("unroll")                                                  \
            for (int ni = 0; ni < 4; ++ni)                                     \
                acc[mi][ni] = __builtin_amdgcn_mfma_f32_16x16x32_fp8_fp8(      \
                    a[mi], b[ni], acc[mi][ni], 0, 0, 0);

    f8frag a0[4], b0[4], a1[4], b1[4];
    LOADF(a0, b0, 0);
    LOADF(a1, b1, 1);
    #pragma unroll
    for (int kw = 0; kw < 8; ++kw) {        // 8 k-windows of 32
        if ((kw & 1) == 0) {
            MM(a0, b0);
            if (kw + 2 < 8) { LOADF(a0, b0, kw + 2); }
        } else {
            MM(a1, b1);
            if (kw + 2 < 8) { LOADF(a1, b1, kw + 2); }
        }
    }
    #undef LOADF
    #undef MM

    // Epilogue. C/D layout: col = lane&15, row = (lane>>4)*4 + j  [m89/m91]
    int frow = l & 15;
    int k16  = l >> 4;
    int rbase = brow + wr * 64 + k16 * 4;
    int cb    = bcol + wc * 64 + frow;
    float csum[4] = {0.f, 0.f, 0.f, 0.f};
    float rv = 0.f;
    #pragma unroll
    for (int mi = 0; mi < 4; ++mi) {
        #pragma unroll
        for (int j = 0; j < 4; ++j) {
            int grow = rbase + mi * 16 + j;
            float rp = 0.f;
            #pragma unroll
            for (int ni = 0; ni < 4; ++ni) {
                float e = exp2f(acc[mi][ni][j] * EXP_SCALE);
                e = (grow == cb + ni * 16) ? 0.f : e;   // main diagonal only
                csum[ni] += e;
                rp += e;
            }
            rp += __shfl_xor(rp, 1);
            rp += __shfl_xor(rp, 2);
            rp += __shfl_xor(rp, 4);
            rp += __shfl_xor(rp, 8);
            rv = (frow == mi * 4 + j) ? rp : rv;
        }
    }
    // column totals within wave: reduce over k16 groups
    #pragma unroll
    for (int ni = 0; ni < 4; ++ni) {
        csum[ni] += __shfl_xor(csum[ni], 16);
        csum[ni] += __shfl_xor(csum[ni], 32);
    }
    float cv = csum[0];
    #pragma unroll
    for (int v = 1; v < 4; ++v) cv = (k16 == v) ? csum[v] : cv;  // static idx

    // cross-wave combine through LDS
    red[w * 64 + l] = cv;               // col partial: col = bcol+(w&1)*64+l
    int roff = k16 * 4 + (frow >> 2) * 16 + (frow & 3);  // bijection on 0..63
    red[256 + w * 64 + roff] = rv;      // row partial: row = brow+(w>>1)*64+roff
    __syncthreads();

    if (w < 2) {        // waves 0,1: finalize 128 column atomics
        float v = red[w * 64 + l] + red[(w + 2) * 64 + l];
        atomicAdd(&rowsum[bcol + w * 64 + l], v);
    } else if (!diag) { // waves 2,3: finalize 128 row atomics
        int half = w - 2;
        float v = red[256 + (2 * half) * 64 + l] + red[256 + (2 * half + 1) * 64 + l];
        atomicAdd(&rowsum[brow + half * 64 + l], v);
    }
}

// ---------------- Kernel C: finalize ----------------
__global__ __launch_bounds__(256) void finalize_kernel(
    const float* __restrict__ rowsum, const float* __restrict__ pdot,
    float* __restrict__ out) {
    int t = threadIdx.x;
    const float4* rs4 = (const float4*)rowsum;
    const float4* pd4 = (const float4*)pdot;
    float s = 0.f, p = 0.f;
    for (int r = t; r < N2 / 4; r += 256) {
        float4 v = rs4[r];
        s += logf(v.x) + logf(v.y) + logf(v.z) + logf(v.w);
    }
    for (int r = t; r < NPAIR / 4; r += 256) {
        float4 v = pd4[r];
        p += v.x + v.y + v.z + v.w;
    }
    #pragma unroll
    for (int off = 32; off; off >>= 1) {
        s += __shfl_xor(s, off);
        p += __shfl_xor(p, off);
    }
    __shared__ float reds[4], redp[4];
    if ((t & 63) == 0) { reds[t >> 6] = s; redp[t >> 6] = p; }
    __syncthreads();
    if (t == 0) {
        float S = reds[0] + reds[1] + reds[2] + reds[3];
        float P = redp[0] + redp[1] + redp[2] + redp[3];
        // loss = (sum log D - (2/T)*2*sum(dp)) / 2N ; (2/T)*2 folded: 4*P
        out[0] = (S - 4.0f * P) / (float)N2;
    }
}

extern "C" void kernel_launch(void* const* d_in, const int* in_sizes, int n_in,
                              void* d_out, int out_size, void* d_ws, size_t ws_size,
                              hipStream_t stream) {
    const float* emb_i = (const float*)d_in[0];
    const float* emb_j = (const float*)d_in[1];
    float* out = (float*)d_out;

    char* ws = (char*)d_ws;
    float*    rowsum = (float*)ws;                    // 8192 * 4 B
    float*    pdot   = (float*)(ws + 32768);          // 4096 * 4 B
    uint8_t*  reps   = (uint8_t*)(ws + 65536);        // 8192*256*1 B (fp8 tiled)

    normalize_kernel<<<NPAIR / 4, 256, 0, stream>>>(emb_i, emb_j, reps, pdot,
                                                    rowsum);

    simexp_kernel<<<NBLOCKS, 256, 0, stream>>>(reps, rowsum);

    finalize_kernel<<<1, 256, 0, stream>>>(rowsum, pdot, out);
}

// Round 11
// 39.313 us; speedup vs baseline: 1.5042x; 1.1353x over previous
//
#include <hip/hip_runtime.h>
#include <hip/hip_bf16.h>
#include <hip/hip_fp8.h>
#include <stdint.h>

#define NPAIR 4096
#define N2    8192      // 2N rows
#define DIM   256
#define NTILE 8256      // 128*129/2 upper-triangle 64x64 tiles
// exp(x/T) = exp2(x * log2(e)/T), T=0.5
#define EXP_SCALE 2.8853900817779268f

typedef long  f8frag;   // 8 fp8 elems = 2 VGPR (A/B operand of 16x16x32 fp8)
typedef float f32x4 __attribute__((ext_vector_type(4)));

static __device__ __forceinline__ uint8_t f2fp8(float f) {
    __hip_fp8_e4m3 v(f);                 // OCP e4m3fn, RNE saturating
    return *reinterpret_cast<uint8_t*>(&v);
}

// reps is stored FRAGMENT-TILED fp8: byte index of (row i, dim d) =
//   ((i>>4)*8 + (d>>5))*512 + ((d>>3)&3)*128 + (i&15)*8 + (d&7)
// so an MFMA fragment (16 rows x 32 k; lane l -> row l&15, k-slot l>>4)
// is the contiguous 512B block at tile(i>>4, d>>5): lane l reads 8B at
// base + l*8. One fully-coalesced 512B load per wave instruction.

// ---------------- Kernel A: normalize rows + positive dot + zero rowsum ----
__global__ __launch_bounds__(256) void normalize_kernel(
    const float* __restrict__ emb_i, const float* __restrict__ emb_j,
    uint8_t* __restrict__ reps, float* __restrict__ pdot,
    float* __restrict__ rowsum) {
    int i = blockIdx.x * 4 + (threadIdx.x >> 6);
    int l = threadIdx.x & 63;       // 0..63, 4 floats each
    float4 a = ((const float4*)(emb_i + (size_t)i * DIM))[l];
    float4 b = ((const float4*)(emb_j + (size_t)i * DIM))[l];
    float si = a.x*a.x + a.y*a.y + a.z*a.z + a.w*a.w;
    float sj = b.x*b.x + b.y*b.y + b.z*b.z + b.w*b.w;
    float dp = a.x*b.x + a.y*b.y + a.z*b.z + a.w*b.w;
    #pragma unroll
    for (int off = 32; off; off >>= 1) {
        si += __shfl_xor(si, off);
        sj += __shfl_xor(sj, off);
        dp += __shfl_xor(dp, off);
    }
    float ri = 1.0f / fmaxf(sqrtf(si), 1e-12f);
    float rj = 1.0f / fmaxf(sqrtf(sj), 1e-12f);

    uchar4 ua, ub;
    ua.x = f2fp8(a.x * ri); ua.y = f2fp8(a.y * ri);
    ua.z = f2fp8(a.z * ri); ua.w = f2fp8(a.w * ri);
    ub.x = f2fp8(b.x * rj); ub.y = f2fp8(b.y * rj);
    ub.z = f2fp8(b.z * rj); ub.w = f2fp8(b.w * rj);

    // tiled store: row i, d0 = 4l -> ktile l>>3, slot (l>>1)&3, e (l&1)*4
    int ii = i + NPAIR;
    int idxA = (((i  >> 4) * 8 + (l >> 3)) * 512) + ((l >> 1) & 3) * 128
             + (i  & 15) * 8 + (l & 1) * 4;
    int idxB = (((ii >> 4) * 8 + (l >> 3)) * 512) + ((l >> 1) & 3) * 128
             + (ii & 15) * 8 + (l & 1) * 4;
    *(uchar4*)(reps + idxA) = ua;
    *(uchar4*)(reps + idxB) = ub;

    if (l == 0) pdot[i] = dp * ri * rj;
    if (l < 2)  rowsum[2 * i + l] = 0.f;
}

// ---------- Kernel B: BARRIER-FREE per-wave 64x64 triangle tiles ----------
// One wave per 64x64 sim tile (8256 tiles, 4 independent waves per block;
// NO __shared__, NO __syncthreads). Fragments load direct from L2 (reps =
// 2 MB fp8, fragment-tiled); depth-2 register pipeline; setprio(1) around
// the MFMA cluster (independent-wave regime, T5/m191). Anti-diagonal tile
// order keeps concurrent tiles' atomic targets disjoint. Each wave ends
// with exactly 2 atomics per lane (64 col + 64 row totals, bijective);
// diagonal tiles mask the main diagonal and skip row atomics (symmetry
// gives rows of the strict upper part via column sums of the transpose).
__global__ __launch_bounds__(256, 4) void simexp_kernel(
    const uint8_t* __restrict__ reps, float* __restrict__ rowsum) {
    int t = threadIdx.x;
    int l = t & 63;
    int w = t >> 6;

    // anti-diagonal decode over n=128 tile grid: C(d) = d*(257-d)/2
    int idx = blockIdx.x * 4 + w;
    int d = (int)((257.0f - sqrtf(257.0f * 257.0f - 8.0f * (float)idx)) * 0.5f);
    while (d * (257 - d) / 2 > idx) --d;
    while ((d + 1) * (256 - d) / 2 <= idx) ++d;
    int i0 = idx - d * (257 - d) / 2;
    int brow = i0 * 64;
    int bcol = (i0 + d) * 64;
    bool diag = (d == 0);

    // row-tile indices for this wave's A (rows) and B (cols) fragments
    int R0A = i0 * 4;             // + q
    int R0B = (i0 + d) * 4;       // + q

    f32x4 acc[4][4];
    #pragma unroll
    for (int mi = 0; mi < 4; ++mi)
        #pragma unroll
        for (int ni = 0; ni < 4; ++ni)
            acc[mi][ni] = (f32x4){0.f, 0.f, 0.f, 0.f};

    // fragment tile (rowtile R, ktile kw): contiguous 512B at byte
    // (R*8 + kw)*512; lane l reads 8B at + l*8
    #define LOADF(dstA, dstB, kw)                                              \
        _Pragma("unroll")                                                      \
        for (int q = 0; q < 4; ++q) {                                          \
            dstA[q] = ((const f8frag*)(reps +                                  \
                       (size_t)(((R0A + q) * 8 + (kw)) * 512)))[l];            \
            dstB[q] = ((const f8frag*)(reps +                                  \
                       (size_t)(((R0B + q) * 8 + (kw)) * 512)))[l];            \
        }
    #define MM(a, b)                                                           \
        __builtin_amdgcn_s_setprio(1);                                         \
        _Pragma("unroll")                                                      \
        for (int mi = 0; mi < 4; ++mi)                                         \
            _Pragma("unroll")                                                  \
            for (int ni = 0; ni < 4; ++ni)                                     \
                acc[mi][ni] = __builtin_amdgcn_mfma_f32_16x16x32_fp8_fp8(      \
                    a[mi], b[ni], acc[mi][ni], 0, 0, 0);                       \
        __builtin_amdgcn_s_setprio(0);

    f8frag a0[4], b0[4], a1[4], b1[4];
    LOADF(a0, b0, 0);
    LOADF(a1, b1, 1);
    #pragma unroll
    for (int kw = 0; kw < 8; ++kw) {        // 8 k-windows of 32
        if ((kw & 1) == 0) {
            MM(a0, b0);
            if (kw + 2 < 8) { LOADF(a0, b0, kw + 2); }
        } else {
            MM(a1, b1);
            if (kw + 2 < 8) { LOADF(a1, b1, kw + 2); }
        }
    }
    #undef LOADF
    #undef MM

    // Epilogue. C/D layout: col = lane&15, row = (lane>>4)*4 + j  [m89/m91]
    int frow = l & 15;
    int k16  = l >> 4;
    int rbase = brow + k16 * 4;
    int cb    = bcol + frow;
    float csum[4] = {0.f, 0.f, 0.f, 0.f};
    float rv = 0.f;
    #pragma unroll
    for (int mi = 0; mi < 4; ++mi) {
        #pragma unroll
        for (int j = 0; j < 4; ++j) {
            int grow = rbase + mi * 16 + j;
            float rp = 0.f;
            #pragma unroll
            for (int ni = 0; ni < 4; ++ni) {
                float e = exp2f(acc[mi][ni][j] * EXP_SCALE);
                e = (grow == cb + ni * 16) ? 0.f : e;   // main diagonal only
                csum[ni] += e;
                rp += e;
            }
            rp += __shfl_xor(rp, 1);
            rp += __shfl_xor(rp, 2);
            rp += __shfl_xor(rp, 4);
            rp += __shfl_xor(rp, 8);
            rv = (frow == mi * 4 + j) ? rp : rv;
        }
    }
    // column totals: reduce over k16 groups -> lane's own column = l
    #pragma unroll
    for (int ni = 0; ni < 4; ++ni) {
        csum[ni] += __shfl_xor(csum[ni], 16);
        csum[ni] += __shfl_xor(csum[ni], 32);
    }
    float cv = csum[0];
    #pragma unroll
    for (int v = 1; v < 4; ++v) cv = (k16 == v) ? csum[v] : cv;  // static idx
    atomicAdd(&rowsum[bcol + k16 * 16 + frow], cv);   // 64 disjoint cols

    if (!diag) {
        // lane holds row total for row (frow>>2)*16 + k16*4 + (frow&3)
        int grow = brow + (frow >> 2) * 16 + k16 * 4 + (frow & 3);
        atomicAdd(&rowsum[grow], rv);                 // 64 disjoint rows
    }
}

// ---------------- Kernel C: finalize ----------------
__global__ __launch_bounds__(256) void finalize_kernel(
    const float* __restrict__ rowsum, const float* __restrict__ pdot,
    float* __restrict__ out) {
    int t = threadIdx.x;
    const float4* rs4 = (const float4*)rowsum;
    const float4* pd4 = (const float4*)pdot;
    float s = 0.f, p = 0.f;
    for (int r = t; r < N2 / 4; r += 256) {
        float4 v = rs4[r];
        s += __logf(v.x) + __logf(v.y) + __logf(v.z) + __logf(v.w);
    }
    for (int r = t; r < NPAIR / 4; r += 256) {
        float4 v = pd4[r];
        p += v.x + v.y + v.z + v.w;
    }
    #pragma unroll
    for (int off = 32; off; off >>= 1) {
        s += __shfl_xor(s, off);
        p += __shfl_xor(p, off);
    }
    __shared__ float reds[4], redp[4];
    if ((t & 63) == 0) { reds[t >> 6] = s; redp[t >> 6] = p; }
    __syncthreads();
    if (t == 0) {
        float S = reds[0] + reds[1] + reds[2] + reds[3];
        float P = redp[0] + redp[1] + redp[2] + redp[3];
        // loss = (sum log D - (2/T)*2*sum(dp)) / 2N ; (2/T)*2 folded: 4*P
        out[0] = (S - 4.0f * P) / (float)N2;
    }
}

extern "C" void kernel_launch(void* const* d_in, const int* in_sizes, int n_in,
                              void* d_out, int out_size, void* d_ws, size_t ws_size,
                              hipStream_t stream) {
    const float* emb_i = (const float*)d_in[0];
    const float* emb_j = (const float*)d_in[1];
    float* out = (float*)d_out;

    char* ws = (char*)d_ws;
    float*    rowsum = (float*)ws;                    // 8192 * 4 B
    float*    pdot   = (float*)(ws + 32768);          // 4096 * 4 B
    uint8_t*  reps   = (uint8_t*)(ws + 65536);        // 8192*256*1 B (fp8 tiled)

    normalize_kernel<<<NPAIR / 4, 256, 0, stream>>>(emb_i, emb_j, reps, pdot,
                                                    rowsum);

    simexp_kernel<<<NTILE / 4, 256, 0, stream>>>(reps, rowsum);

    finalize_kernel<<<1, 256, 0, stream>>>(rowsum, pdot, out);
}